// Round 22
// baseline (153.671 us; speedup 1.0000x reference)
//
#include <hip/hip_runtime.h>
#include <hip/hip_cooperative_groups.h>

namespace cg = cooperative_groups;

#define NN 4096
#define FIN 256
#define FOUT 64
#define NH 4
#define CAP 128    // max edges/row; Binomial(4096,0.01) P(>127) ~ 1e-30
#define WR2 130    // padded shorts per half-K transposed-w row (260 B)
#define PRB 512    // producer blocks (hprime): (head, 32-node group)

typedef __attribute__((ext_vector_type(8))) short bf16x8;
typedef __attribute__((ext_vector_type(4))) float f32x4;

__device__ __forceinline__ unsigned short f2bf(float f) {   // RNE f32->bf16
    unsigned u = __float_as_uint(f);
    u = (u + 0x7fff + ((u >> 16) & 1)) >> 16;
    return (unsigned short)u;
}
__device__ __forceinline__ float bf2f(unsigned short s) {
    return __uint_as_float((unsigned)s << 16);
}
__device__ __forceinline__ int mbcnt64(unsigned long long m) {
    return __builtin_amdgcn_mbcnt_hi((unsigned)(m >> 32),
           __builtin_amdgcn_mbcnt_lo((unsigned)m, 0));
}

// ---------------------------------------------------------------------------
// Single cooperative kernel.
// Phase A: blocks<PRB run MFMA hprime (r18 math, K split in 2 halves through
//          a 16.6 KB transposed-w LDS stage); ALL blocks grid-stride the adj
//          scan (ballot + chunk-prefix) writing CSR (edges/counts) to global.
// grid.sync()
// Phase B: grid-stride rows: scores from sd -> per-wave softmax -> 8-deep
//          bf16 gather from hb -> out.
// LDS ~19.3 KB, __launch_bounds__(256,8) -> 8 blocks/CU, 32 waves/CU.
// ---------------------------------------------------------------------------
__global__ __launch_bounds__(256, 8) void gat_fused(
    const float* __restrict__ h, const int* __restrict__ adj,
    const float* __restrict__ w, const float* __restrict__ a_src,
    const float* __restrict__ a_dst, const float* __restrict__ bias,
    unsigned short* __restrict__ hb, float* __restrict__ sd,
    int* __restrict__ edges, int* __restrict__ counts,
    float* __restrict__ out)
{
    const int t = threadIdx.x, wv = t >> 6, lane = t & 63;
    const int b = blockIdx.x, grid = gridDim.x;

    __shared__ __align__(16) unsigned short ws[64 * WR2];  // 16,640 B
    __shared__ int   idx_l[CAP];                           // 512 B
    __shared__ float sc[NH][CAP];                          // 2 KB
    __shared__ int   ccnt[16];
    __shared__ float inv_sum[NH];

    // ---------------- Phase A1: hprime (producer blocks) ----------------
    if (b < PRB) {
        const int head = b & 3, n0 = (b >> 2) * 32;
        const int lrow = lane & 15, lk8 = lane >> 4;
        const int obase = (wv & 1) * 32;

        f32x4 acc[2] = {{0.f,0.f,0.f,0.f},{0.f,0.f,0.f,0.f}};
#pragma unroll
        for (int kh = 0; kh < 2; ++kh) {
            // stage this K-half of w[head], transposed ws[o][k']
#pragma unroll
            for (int i = 0; i < 8; ++i) {
                const int k  = (t >> 4) + i * 16;          // 0..127
                const int o4 = (t & 15) * 4;
                const float4 v = *(const float4*)(
                    w + ((size_t)head * FIN + kh * 128 + k) * FOUT + o4);
                ws[(o4 + 0) * WR2 + k] = f2bf(v.x);
                ws[(o4 + 1) * WR2 + k] = f2bf(v.y);
                ws[(o4 + 2) * WR2 + k] = f2bf(v.z);
                ws[(o4 + 3) * WR2 + k] = f2bf(v.w);
            }
            // A-fragments for this half (8 indep float4 loads)
            const float* hrow = h + (size_t)(n0 + (wv >> 1) * 16 + lrow) * FIN
                                  + kh * 128 + lk8 * 8;
            bf16x8 a[4];
#pragma unroll
            for (int j = 0; j < 4; ++j) {
                const float4 v0 = *(const float4*)(hrow + j * 32);
                const float4 v1 = *(const float4*)(hrow + j * 32 + 4);
                union { bf16x8 v; unsigned short s[8]; } u;
                u.s[0] = f2bf(v0.x); u.s[1] = f2bf(v0.y);
                u.s[2] = f2bf(v0.z); u.s[3] = f2bf(v0.w);
                u.s[4] = f2bf(v1.x); u.s[5] = f2bf(v1.y);
                u.s[6] = f2bf(v1.z); u.s[7] = f2bf(v1.w);
                a[j] = u.v;
            }
            __syncthreads();
#pragma unroll
            for (int ks = 0; ks < 4; ++ks)
#pragma unroll
                for (int nt = 0; nt < 2; ++nt) {
                    const bf16x8 bf = *(const bf16x8*)
                        &ws[(obase + nt * 16 + lrow) * WR2 + ks * 32 + lk8 * 8];
                    acc[nt] = __builtin_amdgcn_mfma_f32_16x16x32_bf16(
                                  a[ks], bf, acc[nt], 0, 0, 0);
                }
            __syncthreads();
        }

        // epilogue: hb stores + sd logits (sdbuf overlaid on sc)
        const int mbase = n0 + (wv >> 1) * 16 + lk8 * 4;
#pragma unroll
        for (int nt = 0; nt < 2; ++nt)
#pragma unroll
            for (int r = 0; r < 4; ++r)
                hb[((size_t)head * NN + mbase + r) * FOUT + obase + nt * 16 + lrow] =
                    f2bf(acc[nt][r]);

        float (*sdbuf)[2][16][2] = (float (*)[2][16][2])sc;   // 512 B overlay
        float as_nt[2], ad_nt[2];
#pragma unroll
        for (int nt = 0; nt < 2; ++nt) {
            as_nt[nt] = a_src[head * FOUT + obase + nt * 16 + lrow];
            ad_nt[nt] = a_dst[head * FOUT + obase + nt * 16 + lrow];
        }
        float psr[4] = {0.f,0.f,0.f,0.f}, pdr[4] = {0.f,0.f,0.f,0.f};
#pragma unroll
        for (int nt = 0; nt < 2; ++nt)
#pragma unroll
            for (int r = 0; r < 4; ++r) {
                psr[r] = fmaf(acc[nt][r], as_nt[nt], psr[r]);
                pdr[r] = fmaf(acc[nt][r], ad_nt[nt], pdr[r]);
            }
#pragma unroll
        for (int r = 0; r < 4; ++r)
#pragma unroll
            for (int off = 1; off <= 8; off <<= 1) {
                psr[r] += __shfl_xor(psr[r], off, 64);
                pdr[r] += __shfl_xor(pdr[r], off, 64);
            }
        if (lrow == 0)
#pragma unroll
            for (int r = 0; r < 4; ++r) {
                sdbuf[wv >> 1][wv & 1][lk8 * 4 + r][0] = psr[r];
                sdbuf[wv >> 1][wv & 1][lk8 * 4 + r][1] = pdr[r];
            }
        __syncthreads();
        if ((wv & 1) == 0 && lrow == 0) {
            const int p = wv >> 1;
#pragma unroll
            for (int r = 0; r < 4; ++r) {
                const int n = lk8 * 4 + r;
                const int node = n0 + p * 16 + n;
                sd[(size_t)node * 8 + head]     = sdbuf[p][0][n][0] + sdbuf[p][1][n][0];
                sd[(size_t)node * 8 + 4 + head] = sdbuf[p][0][n][1] + sdbuf[p][1][n][1];
            }
        }
        __syncthreads();
    }

    // ---------------- Phase A2: adj scan -> global CSR ----------------
    for (int r = b; r < NN; r += grid) {
        const int4* arow = (const int4*)(adj + (size_t)r * NN);
        int4 a[4];
#pragma unroll
        for (int it = 0; it < 4; ++it) a[it] = arow[wv * 256 + it * 64 + lane];

        int myoff[4];
#pragma unroll
        for (int it = 0; it < 4; ++it) {
            const unsigned long long b0 = __ballot(a[it].x != 0);
            const unsigned long long b1 = __ballot(a[it].y != 0);
            const unsigned long long b2 = __ballot(a[it].z != 0);
            const unsigned long long b3 = __ballot(a[it].w != 0);
            myoff[it] = mbcnt64(b0) + mbcnt64(b1) + mbcnt64(b2) + mbcnt64(b3);
            if (lane == 0)
                ccnt[wv * 4 + it] = __popcll(b0) + __popcll(b1) +
                                    __popcll(b2) + __popcll(b3);
        }
        __syncthreads();

        int cb[4];
        int s = 0;
#pragma unroll
        for (int k = 0; k < 16; ++k) {
            if ((k >> 2) == wv) cb[k & 3] = s;
            s += ccnt[k];
        }
        if (t == 0) counts[r] = s;

        int* erow = edges + (size_t)r * CAP;
#pragma unroll
        for (int it = 0; it < 4; ++it) {
            int p = cb[it] + myoff[it];
            const int col0 = (wv * 256 + it * 64 + lane) * 4;
            if (a[it].x) { if (p < CAP) erow[p] = col0;     ++p; }
            if (a[it].y) { if (p < CAP) erow[p] = col0 + 1; ++p; }
            if (a[it].z) { if (p < CAP) erow[p] = col0 + 2; ++p; }
            if (a[it].w) { if (p < CAP) erow[p] = col0 + 3; ++p; }
        }
        __syncthreads();
    }

    cg::this_grid().sync();

    // ---------------- Phase B: per-row tail ----------------
    for (int r = b; r < NN; r += grid) {
        const int cnt  = min(counts[r], CAP);
        const int cpad = (cnt + 7) & ~7;

        if (t < cnt) {
            const int j = edges[(size_t)r * CAP + t];
            idx_l[t] = j;
            const float4 sv = *(const float4*)(sd + (size_t)r * 8);
            const float4 dv = *(const float4*)(sd + (size_t)j * 8 + 4);
            const float s0 = sv.x + dv.x, s1 = sv.y + dv.y;
            const float s2 = sv.z + dv.z, s3 = sv.w + dv.w;
            sc[0][t] = (s0 >= 0.f) ? s0 : 0.2f * s0;
            sc[1][t] = (s1 >= 0.f) ? s1 : 0.2f * s1;
            sc[2][t] = (s2 >= 0.f) ? s2 : 0.2f * s2;
            sc[3][t] = (s3 >= 0.f) ? s3 : 0.2f * s3;
        } else if (t < cpad) {
            idx_l[t] = 0;
#pragma unroll
            for (int hh = 0; hh < NH; ++hh) sc[hh][t] = 0.f;
        }
        __syncthreads();

        {   // per-head softmax (wave = head)
            float m = -3.4e38f;
            for (int p = lane; p < cnt; p += 64) m = fmaxf(m, sc[wv][p]);
#pragma unroll
            for (int off = 32; off >= 1; off >>= 1)
                m = fmaxf(m, __shfl_xor(m, off, 64));
            float e = 0.f;
            for (int p = lane; p < cnt; p += 64) {
                const float v = __expf(sc[wv][p] - m);
                sc[wv][p] = v;
                e += v;
            }
#pragma unroll
            for (int off = 32; off >= 1; off >>= 1) e += __shfl_xor(e, off, 64);
            if (lane == 0) inv_sum[wv] = 1.f / e;
        }
        __syncthreads();

        // gather (wave = head, lane = o), 8 rows in flight
        float accv = 0.f;
        const unsigned short* hp = hb + (size_t)(wv * NN) * FOUT + lane;
        for (int p0 = 0; p0 < cpad; p0 += 8) {
            int jj[8]; unsigned short vv[8]; float ww[8];
#pragma unroll
            for (int k = 0; k < 8; ++k) jj[k] = idx_l[p0 + k];
#pragma unroll
            for (int k = 0; k < 8; ++k) vv[k] = hp[(size_t)jj[k] * FOUT];
#pragma unroll
            for (int k = 0; k < 8; ++k) ww[k] = sc[wv][p0 + k];
#pragma unroll
            for (int k = 0; k < 8; ++k) accv = fmaf(ww[k], bf2f(vv[k]), accv);
        }
        out[(size_t)r * (NH * FOUT) + wv * FOUT + lane] =
            accv * inv_sum[wv] + bias[lane];
        __syncthreads();
    }
}

extern "C" void kernel_launch(void* const* d_in, const int* in_sizes, int n_in,
                              void* d_out, int out_size, void* d_ws, size_t ws_size,
                              hipStream_t stream) {
    const float* h     = (const float*)d_in[0];
    const int*   adj   = (const int*)d_in[1];
    const float* w     = (const float*)d_in[2];
    const float* a_src = (const float*)d_in[3];
    const float* a_dst = (const float*)d_in[4];
    const float* bias  = (const float*)d_in[5];
    float* out = (float*)d_out;

    unsigned short* hb = (unsigned short*)d_ws;                 // 2 MB bf16 h'
    float* sd          = (float*)(hb + (size_t)NH * NN * FOUT); // NN*8 floats
    int*   edges       = (int*)(sd + (size_t)NN * 8);           // NN*CAP = 2 MB
    int*   counts      = edges + (size_t)NN * CAP;              // NN ints

    int occ = 0;
    hipOccupancyMaxActiveBlocksPerMultiprocessor(&occ, gat_fused, 256, 0);
    if (occ < 2) occ = 2;               // floor (expect 8)
    int grid = occ * 256;
    if (grid > 2048) grid = 2048;

    void* args[] = {(void*)&h, (void*)&adj, (void*)&w, (void*)&a_src,
                    (void*)&a_dst, (void*)&bias, (void*)&hb, (void*)&sd,
                    (void*)&edges, (void*)&counts, (void*)&out};
    hipLaunchCooperativeKernel((void*)gat_fused, dim3(grid), dim3(256),
                               args, 0, stream);
}

// Round 23
// 39.079 us; speedup vs baseline: 3.9323x; 3.9323x over previous
//
#include <hip/hip_runtime.h>

#define NN 4096
#define FIN 256
#define FOUT 64
#define NH 4
#define CAP2 96    // max edges per HALF row; Binomial(2048,0.01) mean 20.5
#define WROW 258   // padded shorts per ws row (516 B -> bank-spread writes)

typedef __attribute__((ext_vector_type(8))) short bf16x8;
typedef __attribute__((ext_vector_type(4))) float f32x4;

__device__ __forceinline__ unsigned short f2bf(float f) {   // RNE f32->bf16
    unsigned u = __float_as_uint(f);
    u = (u + 0x7fff + ((u >> 16) & 1)) >> 16;
    return (unsigned short)u;
}
__device__ __forceinline__ float bf2f(unsigned short s) {
    return __uint_as_float((unsigned)s << 16);
}
__device__ __forceinline__ int mbcnt64(unsigned long long m) {
    return __builtin_amdgcn_mbcnt_hi((unsigned)(m >> 32),
           __builtin_amdgcn_mbcnt_lo((unsigned)m, 0));
}

// ---------------------------------------------------------------------------
// K1: MFMA hprime (r18 verbatim). Outputs bf16 hb + node-major sd.
// ---------------------------------------------------------------------------
__global__ __launch_bounds__(256) void gat_hprime(
    const float* __restrict__ h, const float* __restrict__ w,
    const float* __restrict__ a_src, const float* __restrict__ a_dst,
    unsigned short* __restrict__ hb, float* __restrict__ sd)
{
    const int b = blockIdx.x, t = threadIdx.x;
    const int head = b & 3, n0 = (b >> 2) * 32;
    const int wv = t >> 6, lane = t & 63;
    const int lrow = lane & 15, lk8 = lane >> 4;

    __shared__ __align__(16) unsigned short ws[64 * WROW];  // 33 KB
    __shared__ float sdbuf[2][2][16][2];

#pragma unroll
    for (int i = 0; i < 16; ++i) {
        const int k  = (t >> 4) + i * 16;
        const int o4 = (t & 15) * 4;
        const float4 v = *(const float4*)(w + ((size_t)head * FIN + k) * FOUT + o4);
        ws[(o4 + 0) * WROW + k] = f2bf(v.x);
        ws[(o4 + 1) * WROW + k] = f2bf(v.y);
        ws[(o4 + 2) * WROW + k] = f2bf(v.z);
        ws[(o4 + 3) * WROW + k] = f2bf(v.w);
    }

    const float* hrow = h + (size_t)(n0 + (wv >> 1) * 16 + lrow) * FIN + lk8 * 8;
    bf16x8 a[8];
#pragma unroll
    for (int ks = 0; ks < 8; ++ks) {
        const float4 v0 = *(const float4*)(hrow + ks * 32);
        const float4 v1 = *(const float4*)(hrow + ks * 32 + 4);
        union { bf16x8 v; unsigned short s[8]; } u;
        u.s[0] = f2bf(v0.x); u.s[1] = f2bf(v0.y);
        u.s[2] = f2bf(v0.z); u.s[3] = f2bf(v0.w);
        u.s[4] = f2bf(v1.x); u.s[5] = f2bf(v1.y);
        u.s[6] = f2bf(v1.z); u.s[7] = f2bf(v1.w);
        a[ks] = u.v;
    }
    __syncthreads();

    const int obase = (wv & 1) * 32;
    f32x4 acc[2] = {{0.f,0.f,0.f,0.f},{0.f,0.f,0.f,0.f}};
#pragma unroll
    for (int ks = 0; ks < 8; ++ks) {
#pragma unroll
        for (int nt = 0; nt < 2; ++nt) {
            const bf16x8 bf = *(const bf16x8*)
                &ws[(obase + nt * 16 + lrow) * WROW + ks * 32 + lk8 * 8];
            acc[nt] = __builtin_amdgcn_mfma_f32_16x16x32_bf16(a[ks], bf, acc[nt], 0, 0, 0);
        }
    }

    const int mbase = n0 + (wv >> 1) * 16 + lk8 * 4;
#pragma unroll
    for (int nt = 0; nt < 2; ++nt)
#pragma unroll
        for (int r = 0; r < 4; ++r)
            hb[((size_t)head * NN + mbase + r) * FOUT + obase + nt * 16 + lrow] =
                f2bf(acc[nt][r]);

    float as_nt[2], ad_nt[2];
#pragma unroll
    for (int nt = 0; nt < 2; ++nt) {
        as_nt[nt] = a_src[head * FOUT + obase + nt * 16 + lrow];
        ad_nt[nt] = a_dst[head * FOUT + obase + nt * 16 + lrow];
    }
    float psr[4] = {0.f,0.f,0.f,0.f}, pdr[4] = {0.f,0.f,0.f,0.f};
#pragma unroll
    for (int nt = 0; nt < 2; ++nt)
#pragma unroll
        for (int r = 0; r < 4; ++r) {
            psr[r] = fmaf(acc[nt][r], as_nt[nt], psr[r]);
            pdr[r] = fmaf(acc[nt][r], ad_nt[nt], pdr[r]);
        }
#pragma unroll
    for (int r = 0; r < 4; ++r)
#pragma unroll
        for (int off = 1; off <= 8; off <<= 1) {
            psr[r] += __shfl_xor(psr[r], off, 64);
            pdr[r] += __shfl_xor(pdr[r], off, 64);
        }
    if (lrow == 0)
#pragma unroll
        for (int r = 0; r < 4; ++r) {
            sdbuf[wv >> 1][wv & 1][lk8 * 4 + r][0] = psr[r];
            sdbuf[wv >> 1][wv & 1][lk8 * 4 + r][1] = pdr[r];
        }
    __syncthreads();
    if ((wv & 1) == 0 && lrow == 0) {
        const int p = wv >> 1;
#pragma unroll
        for (int r = 0; r < 4; ++r) {
            const int n = lk8 * 4 + r;
            const int node = n0 + p * 16 + n;
            sd[(size_t)node * 8 + head]     = sdbuf[p][0][n][0] + sdbuf[p][1][n][0];
            sd[(size_t)node * 8 + 4 + head] = sdbuf[p][0][n][1] + sdbuf[p][1][n][1];
        }
    }
}

// ---------------------------------------------------------------------------
// K2: half-row partials. 8192 blocks = (row, half). Per block: 8 KB adj
// load -> ballot compact (~21 edges) -> scores -> LOCAL softmax (m,s) ->
// UNNORMALIZED partial gather. Writes pacc[256] + m[4],s[4] to workspace.
// Half the latency chain, 2x the phase diversity of row-per-block.
// ---------------------------------------------------------------------------
__global__ __launch_bounds__(256) void gat_part(
    const int* __restrict__ adj, const unsigned short* __restrict__ hb,
    const float* __restrict__ sd,
    float* __restrict__ pacc, float* __restrict__ ms)
{
    const int b = blockIdx.x, t = threadIdx.x, wv = t >> 6, lane = t & 63;
    const int r = b >> 1, half = b & 1;

    __shared__ int   idx_l[CAP2 + 16];
    __shared__ float sc[NH][CAP2 + 16];
    __shared__ int   ccnt[8];
    __shared__ float mloc[NH], sloc[NH];
    __shared__ float accbuf[4][64][4];

    // loads: half row = 512 int4; thread does 2
    const int4* arow = (const int4*)(adj + (size_t)r * NN + half * 2048);
    int4 a[2];
#pragma unroll
    for (int it = 0; it < 2; ++it) a[it] = arow[wv * 128 + it * 64 + lane];

    int myoff[2];
#pragma unroll
    for (int it = 0; it < 2; ++it) {
        const unsigned long long b0 = __ballot(a[it].x != 0);
        const unsigned long long b1 = __ballot(a[it].y != 0);
        const unsigned long long b2 = __ballot(a[it].z != 0);
        const unsigned long long b3 = __ballot(a[it].w != 0);
        myoff[it] = mbcnt64(b0) + mbcnt64(b1) + mbcnt64(b2) + mbcnt64(b3);
        if (lane == 0)
            ccnt[wv * 2 + it] = __popcll(b0) + __popcll(b1) +
                                __popcll(b2) + __popcll(b3);
    }
    __syncthreads();

    int cb[2];
    int s = 0;
#pragma unroll
    for (int k = 0; k < 8; ++k) {
        if ((k >> 1) == wv) cb[k & 1] = s;
        s += ccnt[k];
    }
    const int count = min(s, CAP2);
    const int cpad  = (count + 7) & ~7;

#pragma unroll
    for (int it = 0; it < 2; ++it) {
        int p = cb[it] + myoff[it];
        const int col0 = half * 2048 + (wv * 128 + it * 64 + lane) * 4;
        if (a[it].x) { if (p < CAP2) idx_l[p] = col0;     ++p; }
        if (a[it].y) { if (p < CAP2) idx_l[p] = col0 + 1; ++p; }
        if (a[it].z) { if (p < CAP2) idx_l[p] = col0 + 2; ++p; }
        if (a[it].w) { if (p < CAP2) idx_l[p] = col0 + 3; ++p; }
    }
    __syncthreads();

    if (t < count) {
        const int j = idx_l[t];
        const float4 sv = *(const float4*)(sd + (size_t)r * 8);
        const float4 dv = *(const float4*)(sd + (size_t)j * 8 + 4);
        const float s0 = sv.x + dv.x, s1 = sv.y + dv.y;
        const float s2 = sv.z + dv.z, s3 = sv.w + dv.w;
        sc[0][t] = (s0 >= 0.f) ? s0 : 0.2f * s0;
        sc[1][t] = (s1 >= 0.f) ? s1 : 0.2f * s1;
        sc[2][t] = (s2 >= 0.f) ? s2 : 0.2f * s2;
        sc[3][t] = (s3 >= 0.f) ? s3 : 0.2f * s3;
    } else if (t < cpad + 12 && t < CAP2 + 16) {
        idx_l[t] = 0;
#pragma unroll
        for (int hh = 0; hh < NH; ++hh) sc[hh][t] = 0.f;
    }
    __syncthreads();

    {   // local softmax pieces (wave = head); count may be 0 -> m=-inf, s=0
        float m = -3.4e38f;
        for (int p = lane; p < count; p += 64) m = fmaxf(m, sc[wv][p]);
#pragma unroll
        for (int off = 32; off >= 1; off >>= 1) m = fmaxf(m, __shfl_xor(m, off, 64));
        float e = 0.f;
        for (int p = lane; p < count; p += 64) {
            const float v = __expf(sc[wv][p] - m);
            sc[wv][p] = v;
            e += v;
        }
#pragma unroll
        for (int off = 32; off >= 1; off >>= 1) e += __shfl_xor(e, off, 64);
        if (lane == 0) { mloc[wv] = m; sloc[wv] = e; }
    }
    __syncthreads();

    // unnormalized partial gather: lane = (hh = lane>>4, og = lane&15);
    // wave wv takes p%4==wv; one ushort4 per edge = 4 outs of head hh.
    const int hh = lane >> 4, og = lane & 15;
    const unsigned short* hpb = hb + (size_t)hh * NN * FOUT + og * 4;
    float4 accv = make_float4(0.f, 0.f, 0.f, 0.f);
    for (int p0 = wv; p0 < count; p0 += 16) {
        int jj[4]; float ee[4]; ushort4 hv[4];
#pragma unroll
        for (int k = 0; k < 4; ++k) {
            const int pp = p0 + k * 4;
            const bool act = pp < count;
            jj[k] = act ? idx_l[pp] : 0;
            ee[k] = act ? sc[hh][pp] : 0.f;
        }
#pragma unroll
        for (int k = 0; k < 4; ++k)
            hv[k] = *(const ushort4*)(hpb + (size_t)jj[k] * FOUT);
#pragma unroll
        for (int k = 0; k < 4; ++k) {
            accv.x = fmaf(ee[k], bf2f(hv[k].x), accv.x);
            accv.y = fmaf(ee[k], bf2f(hv[k].y), accv.y);
            accv.z = fmaf(ee[k], bf2f(hv[k].z), accv.z);
            accv.w = fmaf(ee[k], bf2f(hv[k].w), accv.w);
        }
    }
    *(float4*)&accbuf[wv][lane][0] = accv;
    __syncthreads();

    if (wv == 0) {
        float4 r0 = *(const float4*)&accbuf[0][lane][0];
        const float4 r1 = *(const float4*)&accbuf[1][lane][0];
        const float4 r2 = *(const float4*)&accbuf[2][lane][0];
        const float4 r3 = *(const float4*)&accbuf[3][lane][0];
        r0.x += r1.x + r2.x + r3.x;
        r0.y += r1.y + r2.y + r3.y;
        r0.z += r1.z + r2.z + r3.z;
        r0.w += r1.w + r2.w + r3.w;
        *(float4*)(pacc + (size_t)b * 256 + hh * 64 + og * 4) = r0;
        if (lane < 4)      ms[(size_t)b * 8 + lane]     = mloc[lane];
        else if (lane < 8) ms[(size_t)b * 8 + lane]     = sloc[lane - 4];
    }
}

// ---------------------------------------------------------------------------
// K3: merge halves (online-softmax combine) + bias. Block = row.
// ---------------------------------------------------------------------------
__global__ __launch_bounds__(256) void gat_merge(
    const float* __restrict__ pacc, const float* __restrict__ ms,
    const float* __restrict__ bias, float* __restrict__ out)
{
    const int r = blockIdx.x, t = threadIdx.x;
    const int hh = t >> 6, o = t & 63;

    const float m0 = ms[(size_t)(r * 2 + 0) * 8 + hh];
    const float s0 = ms[(size_t)(r * 2 + 0) * 8 + 4 + hh];
    const float m1 = ms[(size_t)(r * 2 + 1) * 8 + hh];
    const float s1 = ms[(size_t)(r * 2 + 1) * 8 + 4 + hh];
    const float m  = fmaxf(m0, m1);
    const float w0 = __expf(m0 - m), w1 = __expf(m1 - m);
    const float inv = 1.f / (w0 * s0 + w1 * s1);

    const float p0 = pacc[(size_t)(r * 2 + 0) * 256 + t];
    const float p1 = pacc[(size_t)(r * 2 + 1) * 256 + t];
    out[(size_t)r * 256 + t] = (w0 * p0 + w1 * p1) * inv + bias[o];
}

extern "C" void kernel_launch(void* const* d_in, const int* in_sizes, int n_in,
                              void* d_out, int out_size, void* d_ws, size_t ws_size,
                              hipStream_t stream) {
    const float* h     = (const float*)d_in[0];
    const int*   adj   = (const int*)d_in[1];
    const float* w     = (const float*)d_in[2];
    const float* a_src = (const float*)d_in[3];
    const float* a_dst = (const float*)d_in[4];
    const float* bias  = (const float*)d_in[5];
    float* out = (float*)d_out;

    unsigned short* hb = (unsigned short*)d_ws;                 // 2 MB bf16 h'
    float* sd   = (float*)(hb + (size_t)NH * NN * FOUT);        // NN*8 floats
    float* pacc = sd + (size_t)NN * 8;                          // 8192*256 = 8 MB
    float* ms   = pacc + (size_t)NN * 2 * 256;                  // 8192*8 floats

    gat_hprime<<<512, 256, 0, stream>>>(h, w, a_src, a_dst, hb, sd);
    gat_part<<<NN * 2, 256, 0, stream>>>(adj, hb, sd, pacc, ms);
    gat_merge<<<NN, 256, 0, stream>>>(pacc, ms, bias, out);
}